// Round 15
// baseline (1103.231 us; speedup 1.0000x reference)
//
#include <hip/hip_runtime.h>
#include <math.h>

#define D_MODEL 256
#define NHEAD   8
#define D_K     32
#define LSEQ    2048
#define BATCH   2
#define ROWS    (BATCH * LSEQ)   // 4096
#define D_FF    1024
#define UTOP    38
#define CAP     128

// ---------------------------------------------------------------------------
// Embedding + positional encoding
// ---------------------------------------------------------------------------
__global__ __launch_bounds__(256) void k_embed(const float* __restrict__ x,
                                               const float* __restrict__ w,
                                               const float* __restrict__ b,
                                               float* __restrict__ h) {
    int row = blockIdx.x;           // b*L + l
    int l   = row & (LSEQ - 1);
    int d   = threadIdx.x;
    __shared__ float xs[32];
    if (d < 32) xs[d] = x[row * 32 + d];
    __syncthreads();
    float acc = 0.f;
#pragma unroll
    for (int i = 0; i < 32; ++i) acc += xs[i] * w[i * D_MODEL + d];
    acc = (acc + b[d]) * 16.0f;     // sqrt(256)
    int m = d >> 1;
    float div = expf(-(float)(2 * m) * (9.210340371976184f / 256.0f)); // ln(1e4)/256
    float ang = (float)l * div;
    float pe = (d & 1) ? cosf(ang) : sinf(ang);
    h[row * D_MODEL + d] = acc + pe;
}

// ---------------------------------------------------------------------------
// Shared fp32 tiled GEMM body: C[64x64 tile] = A[M,K(lda)] @ W[K,N] (+ bias)
// MODE 0: plain   MODE 1: relu   MODE 2: scatter to q/k/v layout [B,H,L,32]
// ---------------------------------------------------------------------------
template <int MODE>
__device__ __forceinline__ void gemm_body(const float* __restrict__ A, int lda,
                                          const float* __restrict__ W, int N,
                                          const float* __restrict__ bias, bool doBias,
                                          float* __restrict__ C, int K,
                                          int m0, int n0) {
    __shared__ float As[16][68];
    __shared__ float Ws[16][68];
    const int t  = threadIdx.x;
    const int tx = t & 15, ty = t >> 4;
    float acc[4][4] = {};
    for (int k0 = 0; k0 < K; k0 += 16) {
        {
            int mr = t >> 2, kc = (t & 3) * 4;
            float4 av = *(const float4*)&A[(size_t)(m0 + mr) * lda + k0 + kc];
            As[kc + 0][mr] = av.x; As[kc + 1][mr] = av.y;
            As[kc + 2][mr] = av.z; As[kc + 3][mr] = av.w;
            int kr = t >> 4, nc = (t & 15) * 4;
            *(float4*)&Ws[kr][nc] = *(const float4*)&W[(size_t)(k0 + kr) * N + n0 + nc];
        }
        __syncthreads();
#pragma unroll
        for (int k = 0; k < 16; ++k) {
            float4 a4 = *(const float4*)&As[k][ty * 4];
            float4 w4 = *(const float4*)&Ws[k][tx * 4];
            float av[4] = {a4.x, a4.y, a4.z, a4.w};
            float wv[4] = {w4.x, w4.y, w4.z, w4.w};
#pragma unroll
            for (int i = 0; i < 4; ++i)
#pragma unroll
                for (int j = 0; j < 4; ++j) acc[i][j] += av[i] * wv[j];
        }
        __syncthreads();
    }
#pragma unroll
    for (int i = 0; i < 4; ++i) {
        int row = m0 + ty * 4 + i;
#pragma unroll
        for (int j = 0; j < 4; ++j) {
            int col = n0 + tx * 4 + j;
            float v = acc[i][j];
            if (doBias) v += bias[col];
            if (MODE == 1) v = fmaxf(v, 0.f);
            if (MODE == 2) {
                int bb = row >> 11, ll = row & (LSEQ - 1);
                int hh = col >> 5, dd = col & 31;
                C[(((size_t)(bb * NHEAD + hh) * LSEQ) + ll) * D_K + dd] = v;
            } else {
                C[(size_t)row * N + col] = v;
            }
        }
    }
}

// QKV fused: blockIdx.z selects {wq,wk,wv}; scatters to [B,H,L,32] at out+z*1M.
__global__ __launch_bounds__(256) void k_qkv(const float* __restrict__ A,
                                             const float* __restrict__ wq,
                                             const float* __restrict__ wk,
                                             const float* __restrict__ wv,
                                             const float* __restrict__ bq,
                                             const float* __restrict__ bk,
                                             const float* __restrict__ bv,
                                             float* __restrict__ out) {
    int z = blockIdx.z;
    const float* W = z == 0 ? wq : (z == 1 ? wk : wv);
    const float* B = z == 0 ? bq : (z == 1 ? bk : bv);
    gemm_body<2>(A, 256, W, 256, B, true, out + (size_t)z * (1 << 20), 256,
                 blockIdx.x * 64, blockIdx.y * 64);
}

// split-K GEMM: blockIdx.z = K-half; partial z to Cbase + z*1M; bias on z=0 only.
__global__ __launch_bounds__(256) void k_gemm_sk(const float* __restrict__ A, int lda,
                                                 const float* __restrict__ W,
                                                 const float* __restrict__ bias,
                                                 float* __restrict__ Cbase,
                                                 int N, int Ksub) {
    int z = blockIdx.z;
    gemm_body<0>(A + (size_t)z * Ksub, lda, W + (size_t)z * Ksub * N, N, bias, z == 0,
                 Cbase + (size_t)z * (1 << 20), Ksub, blockIdx.x * 64, blockIdx.y * 64);
}

// ff1: relu GEMM, N=1024
__global__ __launch_bounds__(256) void k_ff1(const float* __restrict__ A,
                                             const float* __restrict__ W,
                                             const float* __restrict__ bias,
                                             float* __restrict__ C) {
    gemm_body<1>(A, 256, W, 1024, bias, true, C, 256, blockIdx.x * 64, blockIdx.y * 64);
}

// ---------------------------------------------------------------------------
// Fused ProbSparse attention v12 — ZERO-BARRIER wave-private pipeline.
// Each wave owns 4 query rows and stages its OWN K tiles (8 KB, double-
// buffered in a private LDS region) via 8x global_load_lds; self-paced with
// per-wave counted vmcnt(8). No s_barrier / __syncthreads anywhere: the R14
// bottleneck was the 32-phase 4-wave barrier convoy, not VALU or LDS.
// d-split: lane owns 16 dims of keys 2p, 2p+1 (combine = shfl_xor(32)).
// Keys (4x32) live in AGPRs via fully-unrolled phase loop (static indices).
// Pivot = 38th of 64 lane-maxes (bitonic); push >= pivot from registers;
// exact 38th threshold via 128-wide register bitonic; softmax + PV gather.
// Cost: 4x L2 K-traffic (~2.1 GB, ~60 us L2-pipe, overlapped) for the
// removal of ~64 barrier convoys per block.
// ---------------------------------------------------------------------------
__device__ __forceinline__ unsigned int sortkey(float f) {
    unsigned int u = __float_as_uint(f);
    return (u & 0x80000000u) ? ~u : (u | 0x80000000u);
}
__device__ __forceinline__ float key2f(unsigned int u) {
    unsigned int b = (u & 0x80000000u) ? (u ^ 0x80000000u) : ~u;
    return __uint_as_float(b);
}
__device__ __forceinline__ void gload_lds16(const float* src, float* ldsDst) {
    __builtin_amdgcn_global_load_lds(
        (const __attribute__((address_space(1))) unsigned int*)src,
        (__attribute__((address_space(3))) unsigned int*)ldsDst,
        16, 0, 0);
}

__global__ __launch_bounds__(256, 2) void k_attn(const float* __restrict__ Q,
                                                 const float* __restrict__ Kt,
                                                 const float* __restrict__ Vt,
                                                 float* __restrict__ ctxb) {
    __shared__ float          Kl[4][2][2048];   // 64 KB: per-wave double buffer
    __shared__ unsigned int   lvk[4][4][CAP];   // 8 KB   candidate keys
    __shared__ unsigned short lix[4][4][CAP];   // 4 KB   candidate indices
    __shared__ int            lcnt[4][4];

    const int tid   = threadIdx.x;
    const int lane  = tid & 63;
    const int wid   = tid >> 6;
    // XCD swizzle: grid 2048 = 8 XCDs x 256 (bijective).
    const int lbid  = (blockIdx.x & 7) * 256 + (blockIdx.x >> 3);
    const int bh    = lbid >> 7;                // 16 bh x 128 chunks
    const int chunk = lbid & 127;
    const int row0  = chunk * 16 + wid * 4;     // 4 rows per wave
    const int b     = bh >> 3, hh = bh & 7;
    const int h     = lane >> 5;                // d-half owned by this lane
    const int p     = lane & 31;

    const float* Kb = Kt + (size_t)bh * LSEQ * D_K;
    const float* Vb = Vt + (size_t)bh * LSEQ * D_K;
    const float* qp = Q + ((size_t)bh * LSEQ + row0) * D_K;

    const float scale = 0.17677669529663687f;   // 1/sqrt(32)
    float q0[16], q1[16], q2[16], q3[16];
#pragma unroll
    for (int i = 0; i < 16; ++i) {
        q0[i] = qp[      h * 16 + i] * scale;
        q1[i] = qp[32  + h * 16 + i] * scale;
        q2[i] = qp[64  + h * 16 + i] * scale;
        q3[i] = qp[96  + h * 16 + i] * scale;
    }

    // Wave-private stage of tile T into its slot: 8 granules u=0..7.
    // Granule u holds dim-chunk (u&3) of keys 2p + (u>>2), half h.
#define STAGE(T, SLOT)                                                          \
    {                                                                           \
        _Pragma("unroll")                                                       \
        for (int u = 0; u < 8; ++u) {                                           \
            gload_lds16(Kb + (size_t)(T) * 2048 + (2 * p + (u >> 2)) * 32       \
                            + h * 16 + (u & 3) * 4, &Kl[wid][SLOT][u * 256]);   \
        }                                                                       \
    }

    // ---- single pass: half-dots -> combine -> registers, lane-max ------
    unsigned int k0[32], k1[32], k2[32], k3[32];
    unsigned int lm0 = 0u, lm1 = 0u, lm2 = 0u, lm3 = 0u;

    STAGE(0, 0)
    STAGE(1, 1)

#pragma unroll
    for (int t = 0; t < 32; ++t) {
        const int slot = t & 1;               // literal under full unroll
        if (t < 31) asm volatile("s_waitcnt vmcnt(8)" ::: "memory");
        else        asm volatile("s_waitcnt vmcnt(0)" ::: "memory");
        float a0 = 0.f, a1 = 0.f, a2 = 0.f, a3 = 0.f;   // keys 2p
        float e0 = 0.f, e1 = 0.f, e2 = 0.f, e3 = 0.f;   // keys 2p+1
#pragma unroll
        for (int c = 0; c < 4; ++c) {
            float4 kva = *(const float4*)&Kl[wid][slot][c * 256 + lane * 4];
            float4 kvb = *(const float4*)&Kl[wid][slot][(4 + c) * 256 + lane * 4];
            a0 += q0[c*4+0]*kva.x + q0[c*4+1]*kva.y + q0[c*4+2]*kva.z + q0[c*4+3]*kva.w;
            a1 += q1[c*4+0]*kva.x + q1[c*4+1]*kva.y + q1[c*4+2]*kva.z + q1[c*4+3]*kva.w;
            a2 += q2[c*4+0]*kva.x + q2[c*4+1]*kva.y + q2[c*4+2]*kva.z + q2[c*4+3]*kva.w;
            a3 += q3[c*4+0]*kva.x + q3[c*4+1]*kva.y + q3[c*4+2]*kva.z + q3[c*4+3]*kva.w;
            e0 += q0[c*4+0]*kvb.x + q0[c*4+1]*kvb.y + q0[c*4+2]*kvb.z + q0[c*4+3]*kvb.w;
            e1 += q1[c*4+0]*kvb.x + q1[c*4+1]*kvb.y + q1[c*4+2]*kvb.z + q1[c*4+3]*kvb.w;
            e2 += q2[c*4+0]*kvb.x + q2[c*4+1]*kvb.y + q2[c*4+2]*kvb.z + q2[c*4+3]*kvb.w;
            e3 += q3[c*4+0]*kvb.x + q3[c*4+1]*kvb.y + q3[c*4+2]*kvb.z + q3[c*4+3]*kvb.w;
        }
        // issue next-next tile into the slot we just finished reading
        if (t < 30) STAGE(t + 2, slot)
        {
            float fa = a0 + __shfl_xor(a0, 32);
            float fe = e0 + __shfl_xor(e0, 32);
            k0[t] = sortkey(h ? fe : fa);
            if (k0[t] > lm0) lm0 = k0[t];
            fa = a1 + __shfl_xor(a1, 32);
            fe = e1 + __shfl_xor(e1, 32);
            k1[t] = sortkey(h ? fe : fa);
            if (k1[t] > lm1) lm1 = k1[t];
            fa = a2 + __shfl_xor(a2, 32);
            fe = e2 + __shfl_xor(e2, 32);
            k2[t] = sortkey(h ? fe : fa);
            if (k2[t] > lm2) lm2 = k2[t];
            fa = a3 + __shfl_xor(a3, 32);
            fe = e3 + __shfl_xor(e3, 32);
            k3[t] = sortkey(h ? fe : fa);
            if (k3[t] > lm3) lm3 = k3[t];
        }
    }

    // ---- pivot per row: bitonic-sort 64 lane-maxes, broadcast via shfl --
    unsigned int Tpiv[4];
    float        rmaxf[4];
#pragma unroll
    for (int r = 0; r < 4; ++r) {
        unsigned int v = (r == 0) ? lm0 : (r == 1) ? lm1 : (r == 2) ? lm2 : lm3;
#pragma unroll
        for (int k = 2; k <= 64; k <<= 1) {
#pragma unroll
            for (int j = k >> 1; j >= 1; j >>= 1) {
                unsigned int pv = (unsigned int)__shfl_xor((int)v, j);
                bool lower = ((lane & j) == 0);
                bool up    = ((lane & k) == 0);
                unsigned int mn = v < pv ? v : pv;
                unsigned int mx = v < pv ? pv : v;
                v = (lower == up) ? mn : mx;
            }
        }
        Tpiv[r]  = (unsigned int)__shfl((int)v, 26);  // 38th-largest lane-max
        rmaxf[r] = key2f((unsigned int)__shfl((int)v, 63));
    }
    if (lane < 4) lcnt[wid][lane] = 0;

    // ---- push candidates >= pivot from registers (per-wave lists) ------
#define PUSHROW(KARR, R)                                                        \
    _Pragma("unroll")                                                           \
    for (int j = 0; j < 32; ++j) {                                              \
        if (KARR[j] >= Tpiv[R]) {                                               \
            int s = atomicAdd(&lcnt[wid][R], 1);                                \
            if (s < CAP) {                                                      \
                lvk[wid][R][s] = KARR[j];                                       \
                lix[wid][R][s] = (unsigned short)(j * 64 + 2 * p + h);          \
            }                                                                   \
        }                                                                       \
    }
    PUSHROW(k0, 0)
    PUSHROW(k1, 1)
    PUSHROW(k2, 2)
    PUSHROW(k3, 3)

    // ---- per-row: exact threshold via 128-wide bitonic, softmax, PV ----
#pragma unroll
    for (int r = 0; r < 4; ++r) {
        int cnt = lcnt[wid][r]; if (cnt > CAP) cnt = CAP;

        unsigned int v0 = (lane < cnt)      ? lvk[wid][r][lane]      : 0u;
        unsigned int v1 = (64 + lane < cnt) ? lvk[wid][r][64 + lane] : 0u;
#pragma unroll
        for (int k = 2; k <= 128; k <<= 1) {
#pragma unroll
            for (int j = k >> 1; j >= 1; j >>= 1) {
                if (j >= 64) {
                    bool up0 = ((lane & k) == 0);
                    unsigned int mn = v0 < v1 ? v0 : v1;
                    unsigned int mx = v0 < v1 ? v1 : v0;
                    v0 = up0 ? mn : mx;
                    v1 = up0 ? mx : mn;
                } else {
                    unsigned int p0 = (unsigned int)__shfl_xor((int)v0, j);
                    unsigned int p1 = (unsigned int)__shfl_xor((int)v1, j);
                    bool lower = ((lane & j) == 0);
                    bool up0 = (((lane) & k) == 0);
                    bool up1 = (((64 + lane) & k) == 0);
                    v0 = (lower == up0) ? (v0 < p0 ? v0 : p0) : (v0 < p0 ? p0 : v0);
                    v1 = (lower == up1) ? (v1 < p1 ? v1 : p1) : (v1 < p1 ? p1 : v1);
                }
            }
        }
        const unsigned int thrkey = (unsigned int)__shfl((int)v1, 26); // idx 90

        float psum = 0.f;
        for (int i = lane; i < cnt; i += 64) {
            unsigned int key = lvk[wid][r][i];
            if (key >= thrkey) psum += expf(key2f(key) - rmaxf[r]);
        }
#pragma unroll
        for (int off = 32; off >= 1; off >>= 1) psum += __shfl_xor(psum, off);
        float inv = 1.0f / psum;

        float acc = 0.f;
        for (int i = h; i < cnt; i += 2) {
            unsigned int key = lvk[wid][r][i];
            float w = (key >= thrkey) ? expf(key2f(key) - rmaxf[r]) : 0.f;
            acc += w * Vb[(size_t)lix[wid][r][i] * D_K + p];
        }
        acc += __shfl_xor(acc, 32);
        if (lane < 32)
            ctxb[((size_t)(b * LSEQ) + row0 + r) * D_MODEL + hh * D_K + p] = acc * inv;
    }
}

// ---------------------------------------------------------------------------
// Residual add (two partials) + LayerNorm over 256, in place into h.
// ---------------------------------------------------------------------------
__global__ __launch_bounds__(64) void k_addln2(float* __restrict__ h,
                                               const float* __restrict__ a1,
                                               const float* __restrict__ a2,
                                               const float* __restrict__ g,
                                               const float* __restrict__ bb) {
    int row = blockIdx.x, lane = threadIdx.x;
    float4 hv = *(const float4*)&h[(size_t)row * D_MODEL + lane * 4];
    float4 v1 = *(const float4*)&a1[(size_t)row * D_MODEL + lane * 4];
    float4 v2 = *(const float4*)&a2[(size_t)row * D_MODEL + lane * 4];
    float x0 = hv.x + v1.x + v2.x, x1 = hv.y + v1.y + v2.y;
    float x2 = hv.z + v1.z + v2.z, x3 = hv.w + v1.w + v2.w;
    float s = x0 + x1 + x2 + x3;
#pragma unroll
    for (int off = 32; off >= 1; off >>= 1) s += __shfl_xor(s, off);
    float mean = s * (1.0f / 256.0f);
    float d0 = x0 - mean, d1 = x1 - mean, d2 = x2 - mean, d3 = x3 - mean;
    float vs = d0 * d0 + d1 * d1 + d2 * d2 + d3 * d3;
#pragma unroll
    for (int off = 32; off >= 1; off >>= 1) vs += __shfl_xor(vs, off);
    float inv = rsqrtf(vs * (1.0f / 256.0f) + 1e-5f);
    float4 gv = *(const float4*)&g[lane * 4];
    float4 bv = *(const float4*)&bb[lane * 4];
    float4 o;
    o.x = d0 * inv * gv.x + bv.x;
    o.y = d1 * inv * gv.y + bv.y;
    o.z = d2 * inv * gv.z + bv.z;
    o.w = d3 * inv * gv.w + bv.w;
    *(float4*)&h[(size_t)row * D_MODEL + lane * 4] = o;
}

// ---------------------------------------------------------------------------
// Decoder head
// ---------------------------------------------------------------------------
__global__ __launch_bounds__(64) void k_dec(const float* __restrict__ h,
                                            const float* __restrict__ w,
                                            const float* __restrict__ b,
                                            float* __restrict__ out) {
    int row = blockIdx.x, lane = threadIdx.x;
    int c = lane & 7, part = lane >> 3;   // 8 parts x 32 dims
    float acc = 0.f;
    int d0 = part * 32;
#pragma unroll
    for (int dd = 0; dd < 32; ++dd) acc += h[(size_t)row * D_MODEL + d0 + dd] * w[(d0 + dd) * 8 + c];
    acc += __shfl_xor(acc, 8);
    acc += __shfl_xor(acc, 16);
    acc += __shfl_xor(acc, 32);
    if (lane < 8) out[(size_t)row * 8 + c] = acc + b[c];
}

// ---------------------------------------------------------------------------
extern "C" void kernel_launch(void* const* d_in, const int* in_sizes, int n_in,
                              void* d_out, int out_size, void* d_ws, size_t ws_size,
                              hipStream_t stream) {
    const float* x     = (const float*)d_in[0];
    const float* emb_w = (const float*)d_in[1];
    const float* emb_b = (const float*)d_in[2];
    const float* wq    = (const float*)d_in[3];
    const float* bq    = (const float*)d_in[4];
    const float* wk    = (const float*)d_in[5];
    const float* bk    = (const float*)d_in[6];
    const float* wv    = (const float*)d_in[7];
    const float* bv    = (const float*)d_in[8];
    const float* wo    = (const float*)d_in[9];
    const float* bo    = (const float*)d_in[10];
    const float* ln1_g = (const float*)d_in[11];
    const float* ln1_b = (const float*)d_in[12];
    const float* ln2_g = (const float*)d_in[13];
    const float* ln2_b = (const float*)d_in[14];
    const float* ff1_w = (const float*)d_in[15];
    const float* ff1_b = (const float*)d_in[16];
    const float* ff2_w = (const float*)d_in[17];
    const float* ff2_b = (const float*)d_in[18];
    const float* dec_w = (const float*)d_in[19];
    const float* dec_b = (const float*)d_in[20];

    float* ws   = (float*)d_ws;
    float* h    = ws;                      // 4096*256   = 1M floats
    float* qb   = h    + (1 << 20);        // qb/kb/vb: [B,H,L,32] each 1M
    float* kb   = qb   + (1 << 20);
    float* vb   = kb   + (1 << 20);
    float* ctxb = vb   + (1 << 20);
    float* ffb  = ctxb + (1 << 20);        // 4096*1024 = 4M

    k_embed<<<ROWS, 256, 0, stream>>>(x, emb_w, emb_b, h);

    for (int l = 0; l < 2; ++l) {
        const float* wql = wq + (size_t)l * 65536;  const float* bql = bq + l * 256;
        const float* wkl = wk + (size_t)l * 65536;  const float* bkl = bk + l * 256;
        const float* wvl = wv + (size_t)l * 65536;  const float* bvl = bv + l * 256;
        const float* wol = wo + (size_t)l * 65536;  const float* bol = bo + l * 256;

        dim3 gq(64, 4, 3);
        k_qkv<<<gq, 256, 0, stream>>>(h, wql, wkl, wvl, bql, bkl, bvl, qb);

        k_attn<<<NHEAD * BATCH * 128, 256, 0, stream>>>(qb, kb, vb, ctxb);

        // wo: split-K (128 x 2) -> partials in qb, kb (free after attn)
        dim3 gsk(64, 4, 2);
        k_gemm_sk<<<gsk, 256, 0, stream>>>(ctxb, 256, wol, bol, qb, 256, 128);
        k_addln2<<<ROWS, 64, 0, stream>>>(h, qb, kb, ln1_g + l * 256, ln1_b + l * 256);

        dim3 gf1(64, 16);
        k_ff1<<<gf1, 256, 0, stream>>>(h, ff1_w + (size_t)l * 262144, ff1_b + l * 1024, ffb);

        // ff2: split-K (512 x 2) -> partials in qb, kb
        k_gemm_sk<<<gsk, 256, 0, stream>>>(ffb, 1024, ff2_w + (size_t)l * 262144,
                                           ff2_b + l * 256, qb, 256, 512);
        k_addln2<<<ROWS, 64, 0, stream>>>(h, qb, kb, ln2_g + l * 256, ln2_b + l * 256);
    }

    k_dec<<<ROWS, 64, 0, stream>>>(h, dec_w, dec_b, (float*)d_out);
}